// Round 2
// baseline (379.377 us; speedup 1.0000x reference)
//
#include <hip/hip_runtime.h>
#include <hip/hip_cooperative_groups.h>
#include <math.h>

namespace cg = cooperative_groups;

// Problem constants (fixed by setup_inputs)
constexpr int B    = 32;
constexpr int C    = 256;
constexpr int F    = 64;         // C/4
constexpr int HW4  = 1024;       // (64*64)/4 float4 per (b,c) plane
constexpr int P4   = B * HW4;    // 32768 float4 positions per f
constexpr int CHUNKS = 8;        // chunks per f
constexpr int NBLK = F * CHUNKS; // 512 blocks = 2 per CU (co-resident)
constexpr int PPC  = P4 / CHUNKS;   // 4096 float4 positions per chunk
constexpr int PPT  = PPC / 256;     // 16 per thread
constexpr float EPSV = 1e-5f;

__global__ __launch_bounds__(256, 2) void fused_kernel(
    const float* __restrict__ x,
    const float* __restrict__ weight,  // [4,4,F]
    const float* __restrict__ bias,    // [4,F]
    float* __restrict__ out,
    float* __restrict__ ws)            // F*CHUNKS*14 partial sums
{
    const int f     = blockIdx.x & (F - 1);
    const int chunk = blockIdx.x >> 6;
    const int tid   = threadIdx.x;

    const float4* xb = reinterpret_cast<const float4*>(x);
    const size_t qstride = (size_t)F * HW4;  // float4 stride between quaternion components

    // ---------------- Pass 1: stats over this block's slice ----------------
    float acc[14];
#pragma unroll
    for (int i = 0; i < 14; ++i) acc[i] = 0.f;

#pragma unroll 4
    for (int it = 0; it < PPT; ++it) {
        const int p   = chunk * PPC + it * 256 + tid;  // [0, P4)
        const int b   = p >> 10;
        const int hw4 = p & (HW4 - 1);
        const size_t base = ((size_t)b * C + f) * HW4 + hw4;
        float4 v0 = xb[base];
        float4 v1 = xb[base + qstride];
        float4 v2 = xb[base + 2 * qstride];
        float4 v3 = xb[base + 3 * qstride];
#pragma unroll
        for (int l = 0; l < 4; ++l) {
            const float e0 = ((const float*)&v0)[l];
            const float e1 = ((const float*)&v1)[l];
            const float e2 = ((const float*)&v2)[l];
            const float e3 = ((const float*)&v3)[l];
            acc[0] += e0; acc[1] += e1; acc[2] += e2; acc[3] += e3;
            acc[4]  += e0 * e0; acc[5]  += e0 * e1; acc[6]  += e0 * e2; acc[7]  += e0 * e3;
            acc[8]  += e1 * e1; acc[9]  += e1 * e2; acc[10] += e1 * e3;
            acc[11] += e2 * e2; acc[12] += e2 * e3;
            acc[13] += e3 * e3;
        }
    }

    // wave(64) shuffle reduce, then cross-wave via LDS
#pragma unroll
    for (int i = 0; i < 14; ++i) {
#pragma unroll
        for (int off = 32; off >= 1; off >>= 1)
            acc[i] += __shfl_down(acc[i], off, 64);
    }

    __shared__ float red[4][14];
    __shared__ float ssum[14];
    __shared__ float sM[20];

    const int wave = tid >> 6;
    const int lane = tid & 63;
    if (lane == 0) {
#pragma unroll
        for (int i = 0; i < 14; ++i) red[wave][i] = acc[i];
    }
    __syncthreads();
    if (tid < 14) {
        ws[(f * CHUNKS + chunk) * 14 + tid] =
            red[0][tid] + red[1][tid] + red[2][tid] + red[3][tid];
    }

    __threadfence();
    cg::this_grid().sync();

    // ---------------- Tiny solve (redundant across chunks of same f) -------
    if (tid < 14) {
        float s = 0.f;
#pragma unroll
        for (int c = 0; c < CHUNKS; ++c) s += ws[(f * CHUNKS + c) * 14 + tid];
        ssum[tid] = s;
    }
    __syncthreads();

    if (tid == 0) {
        const float invN = 1.0f / (float)(B * HW4 * 4);
        float m[4];
#pragma unroll
        for (int q = 0; q < 4; ++q) m[q] = ssum[q] * invN;

        float cov[4][4];
        {
            int k = 4;
            for (int i = 0; i < 4; ++i)
                for (int j = i; j < 4; ++j) {
                    float cij = ssum[k] * invN - m[i] * m[j];
                    cov[i][j] = cij; cov[j][i] = cij; ++k;
                }
        }
#pragma unroll
        for (int i = 0; i < 4; ++i) cov[i][i] += EPSV;

        float L[4][4] = {};
        for (int i = 0; i < 4; ++i)
            for (int j = 0; j <= i; ++j) {
                float s = cov[i][j];
                for (int k = 0; k < j; ++k) s -= L[i][k] * L[j][k];
                if (i == j) L[i][j] = sqrtf(s);
                else        L[i][j] = s / L[j][j];
            }

        float Li[4][4] = {};
        for (int j = 0; j < 4; ++j) {
            Li[j][j] = 1.0f / L[j][j];
            for (int i = j + 1; i < 4; ++i) {
                float s = 0.f;
                for (int k = j; k < i; ++k) s += L[i][k] * Li[k][j];
                Li[i][j] = -s / L[i][i];
            }
        }

        float M[4][4];
        for (int i = 0; i < 4; ++i)
            for (int j = 0; j < 4; ++j) {
                float s = 0.f;
                for (int k = 0; k < 4; ++k)
                    s += weight[(i * 4 + k) * F + f] * Li[k][j];
                M[i][j] = s;
            }
        for (int i = 0; i < 4; ++i) {
            float ci = bias[i * F + f];
            for (int j = 0; j < 4; ++j) ci -= M[i][j] * m[j];
#pragma unroll
            for (int j = 0; j < 4; ++j) sM[i * 4 + j] = M[i][j];
            sM[16 + i] = ci;
        }
    }
    __syncthreads();

    const float m00 = sM[0],  m01 = sM[1],  m02 = sM[2],  m03 = sM[3];
    const float m10 = sM[4],  m11 = sM[5],  m12 = sM[6],  m13 = sM[7];
    const float m20 = sM[8],  m21 = sM[9],  m22 = sM[10], m23 = sM[11];
    const float m30 = sM[12], m31 = sM[13], m32 = sM[14], m33 = sM[15];
    const float c0 = sM[16], c1 = sM[17], c2 = sM[18], c3 = sM[19];

    float4* ob = reinterpret_cast<float4*>(out);

    // ---------------- Pass 2: transform the same slice (L2/L3 warm) --------
#pragma unroll 2
    for (int it = 0; it < PPT; ++it) {
        const int p   = chunk * PPC + it * 256 + tid;
        const int b   = p >> 10;
        const int hw4 = p & (HW4 - 1);
        const size_t base = ((size_t)b * C + f) * HW4 + hw4;
        float4 v0 = xb[base];
        float4 v1 = xb[base + qstride];
        float4 v2 = xb[base + 2 * qstride];
        float4 v3 = xb[base + 3 * qstride];

        float4 o0, o1, o2, o3;
#pragma unroll
        for (int l = 0; l < 4; ++l) {
            const float e0 = ((const float*)&v0)[l];
            const float e1 = ((const float*)&v1)[l];
            const float e2 = ((const float*)&v2)[l];
            const float e3 = ((const float*)&v3)[l];
            ((float*)&o0)[l] = c0 + m00 * e0 + m01 * e1 + m02 * e2 + m03 * e3;
            ((float*)&o1)[l] = c1 + m10 * e0 + m11 * e1 + m12 * e2 + m13 * e3;
            ((float*)&o2)[l] = c2 + m20 * e0 + m21 * e1 + m22 * e2 + m23 * e3;
            ((float*)&o3)[l] = c3 + m30 * e0 + m31 * e1 + m32 * e2 + m33 * e3;
        }
        ob[base]               = o0;
        ob[base + qstride]     = o1;
        ob[base + 2 * qstride] = o2;
        ob[base + 3 * qstride] = o3;
    }
}

extern "C" void kernel_launch(void* const* d_in, const int* in_sizes, int n_in,
                              void* d_out, int out_size, void* d_ws, size_t ws_size,
                              hipStream_t stream) {
    const float* x      = (const float*)d_in[0];
    const float* weight = (const float*)d_in[1];
    const float* bias   = (const float*)d_in[2];
    float*       out    = (float*)d_out;
    float*       ws     = (float*)d_ws;

    void* args[] = {(void*)&x, (void*)&weight, (void*)&bias, (void*)&out, (void*)&ws};
    hipLaunchCooperativeKernel((const void*)fused_kernel,
                               dim3(NBLK), dim3(256), args, 0, stream);
}

// Round 4
// 262.899 us; speedup vs baseline: 1.4431x; 1.4431x over previous
//
#include <hip/hip_runtime.h>
#include <math.h>

// Problem constants (fixed by setup_inputs)
constexpr int B    = 32;
constexpr int C    = 256;
constexpr int F    = 64;     // C/4
constexpr int HW4  = 1024;   // (64*64)/4 float4 per (b,c) plane
constexpr float EPSV = 1e-5f;

typedef float v4f __attribute__((ext_vector_type(4)));  // native vec for NT stores

// stats: one block per (f, b) pair -> 64*32 = 2048 blocks, 4 float4/thread
// transform: one block per (f, half-plane) -> 64*64 = 4096 blocks, 2 pos/thread

// ---------------- Kernel 1: per-(f,b) 14-way partial reduction ---------------
__global__ __launch_bounds__(256) void stats_kernel(const float* __restrict__ x,
                                                    float* __restrict__ ws) {
    const int f   = blockIdx.x & (F - 1);
    const int b   = blockIdx.x >> 6;       // 0..31
    const int tid = threadIdx.x;

    const v4f* xb = reinterpret_cast<const v4f*>(x);
    const size_t qs    = (size_t)F * HW4;            // stride between q components
    const size_t base0 = ((size_t)b * C + f) * HW4;  // this block's plane for q=0

    float acc[14];
#pragma unroll
    for (int i = 0; i < 14; ++i) acc[i] = 0.f;

    // 4 positions per thread, processed as 2 batches of 8 in-flight loads
#pragma unroll
    for (int half = 0; half < 2; ++half) {
        v4f v[2][4];
#pragma unroll
        for (int it = 0; it < 2; ++it) {
            const size_t base = base0 + (half * 2 + it) * 256 + tid;
            v[it][0] = xb[base];
            v[it][1] = xb[base + qs];
            v[it][2] = xb[base + 2 * qs];
            v[it][3] = xb[base + 3 * qs];
        }
#pragma unroll
        for (int it = 0; it < 2; ++it) {
#pragma unroll
            for (int l = 0; l < 4; ++l) {
                const float e0 = v[it][0][l];
                const float e1 = v[it][1][l];
                const float e2 = v[it][2][l];
                const float e3 = v[it][3][l];
                acc[0] += e0; acc[1] += e1; acc[2] += e2; acc[3] += e3;
                acc[4]  += e0 * e0; acc[5]  += e0 * e1; acc[6]  += e0 * e2; acc[7]  += e0 * e3;
                acc[8]  += e1 * e1; acc[9]  += e1 * e2; acc[10] += e1 * e3;
                acc[11] += e2 * e2; acc[12] += e2 * e3;
                acc[13] += e3 * e3;
            }
        }
    }

    // wave(64) shuffle reduce, then cross-wave via LDS
#pragma unroll
    for (int i = 0; i < 14; ++i) {
#pragma unroll
        for (int off = 32; off >= 1; off >>= 1)
            acc[i] += __shfl_down(acc[i], off, 64);
    }

    __shared__ float red[4][14];
    const int wave = tid >> 6;
    const int lane = tid & 63;
    if (lane == 0) {
#pragma unroll
        for (int i = 0; i < 14; ++i) red[wave][i] = acc[i];
    }
    __syncthreads();
    if (tid < 14) {
        // private partial slot: no atomics, no memset needed
        ws[(size_t)blockIdx.x * 14 + tid] =
            red[0][tid] + red[1][tid] + red[2][tid] + red[3][tid];
    }
}

// ---------------- Kernel 2: per-f mean/cov/Cholesky/compose M,c --------------
__global__ __launch_bounds__(64) void solve_kernel(const float* __restrict__ ws,
                                                   const float* __restrict__ weight, // [4,4,F]
                                                   const float* __restrict__ bias,   // [4,F]
                                                   float* __restrict__ Mc) {         // [F][20]
    const int f = threadIdx.x;
    if (f >= F) return;

    float s[14];
#pragma unroll
    for (int i = 0; i < 14; ++i) s[i] = 0.f;
    for (int b = 0; b < B; ++b) {
        const float* p = ws + ((size_t)(b * F + f)) * 14; // blockIdx = b*64 + f
#pragma unroll
        for (int i = 0; i < 14; ++i) s[i] += p[i];
    }

    const float invN = 1.0f / (float)(B * HW4 * 4);
    float m[4];
#pragma unroll
    for (int q = 0; q < 4; ++q) m[q] = s[q] * invN;

    float cov[4][4];
    {
        int k = 4;
        for (int i = 0; i < 4; ++i)
            for (int j = i; j < 4; ++j) {
                float cij = s[k] * invN - m[i] * m[j];
                cov[i][j] = cij; cov[j][i] = cij; ++k;
            }
    }
#pragma unroll
    for (int i = 0; i < 4; ++i) cov[i][i] += EPSV;

    float L[4][4] = {};
    for (int i = 0; i < 4; ++i)
        for (int j = 0; j <= i; ++j) {
            float t = cov[i][j];
            for (int k = 0; k < j; ++k) t -= L[i][k] * L[j][k];
            if (i == j) L[i][j] = sqrtf(t);
            else        L[i][j] = t / L[j][j];
        }

    float Li[4][4] = {};
    for (int j = 0; j < 4; ++j) {
        Li[j][j] = 1.0f / L[j][j];
        for (int i = j + 1; i < 4; ++i) {
            float t = 0.f;
            for (int k = j; k < i; ++k) t += L[i][k] * Li[k][j];
            Li[i][j] = -t / L[i][i];
        }
    }

    float M[4][4];
    for (int i = 0; i < 4; ++i)
        for (int j = 0; j < 4; ++j) {
            float t = 0.f;
            for (int k = 0; k < 4; ++k)
                t += weight[(i * 4 + k) * F + f] * Li[k][j];
            M[i][j] = t;
        }
    for (int i = 0; i < 4; ++i) {
        float ci = bias[i * F + f];
        for (int j = 0; j < 4; ++j) ci -= M[i][j] * m[j];
#pragma unroll
        for (int j = 0; j < 4; ++j) Mc[f * 20 + i * 4 + j] = M[i][j];
        Mc[f * 20 + 16 + i] = ci;
    }
}

// ---------------- Kernel 3: out = M*x + c, NT stores, 2 pos/thread -----------
__global__ __launch_bounds__(256) void transform_kernel(const float* __restrict__ x,
                                                        const float* __restrict__ Mc,
                                                        float* __restrict__ out) {
    const int f   = blockIdx.x & (F - 1);
    const int c   = blockIdx.x >> 6;       // 0..63: half-plane index
    const int tid = threadIdx.x;

    // uniform (blockIdx-only) indices -> compiler emits scalar loads
    const float* Mf = Mc + f * 20;
    const float m00 = Mf[0],  m01 = Mf[1],  m02 = Mf[2],  m03 = Mf[3];
    const float m10 = Mf[4],  m11 = Mf[5],  m12 = Mf[6],  m13 = Mf[7];
    const float m20 = Mf[8],  m21 = Mf[9],  m22 = Mf[10], m23 = Mf[11];
    const float m30 = Mf[12], m31 = Mf[13], m32 = Mf[14], m33 = Mf[15];
    const float c0 = Mf[16], c1 = Mf[17], c2 = Mf[18], c3 = Mf[19];

    const int b    = c >> 1;
    const int hw0  = (c & 1) * 512 + tid;

    const v4f* xb = reinterpret_cast<const v4f*>(x);
    v4f*       ob = reinterpret_cast<v4f*>(out);
    const size_t qs    = (size_t)F * HW4;
    const size_t base0 = ((size_t)b * C + f) * HW4 + hw0;

    v4f v[2][4];
#pragma unroll
    for (int it = 0; it < 2; ++it) {
        const size_t base = base0 + it * 256;
        v[it][0] = xb[base];
        v[it][1] = xb[base + qs];
        v[it][2] = xb[base + 2 * qs];
        v[it][3] = xb[base + 3 * qs];
    }

#pragma unroll
    for (int it = 0; it < 2; ++it) {
        const size_t base = base0 + it * 256;
        v4f o0, o1, o2, o3;
#pragma unroll
        for (int l = 0; l < 4; ++l) {
            const float e0 = v[it][0][l];
            const float e1 = v[it][1][l];
            const float e2 = v[it][2][l];
            const float e3 = v[it][3][l];
            o0[l] = c0 + m00 * e0 + m01 * e1 + m02 * e2 + m03 * e3;
            o1[l] = c1 + m10 * e0 + m11 * e1 + m12 * e2 + m13 * e3;
            o2[l] = c2 + m20 * e0 + m21 * e1 + m22 * e2 + m23 * e3;
            o3[l] = c3 + m30 * e0 + m31 * e1 + m32 * e2 + m33 * e3;
        }
        __builtin_nontemporal_store(o0, &ob[base]);
        __builtin_nontemporal_store(o1, &ob[base + qs]);
        __builtin_nontemporal_store(o2, &ob[base + 2 * qs]);
        __builtin_nontemporal_store(o3, &ob[base + 3 * qs]);
    }
}

extern "C" void kernel_launch(void* const* d_in, const int* in_sizes, int n_in,
                              void* d_out, int out_size, void* d_ws, size_t ws_size,
                              hipStream_t stream) {
    const float* x      = (const float*)d_in[0];
    const float* weight = (const float*)d_in[1];
    const float* bias   = (const float*)d_in[2];
    float*       out    = (float*)d_out;

    float* ws = (float*)d_ws;            // 2048 * 14 partials
    float* Mc = ws + 2048 * 14;          // F * 20

    stats_kernel<<<dim3(F * B), dim3(256), 0, stream>>>(x, ws);
    solve_kernel<<<dim3(1), dim3(64), 0, stream>>>(ws, weight, bias, Mc);
    transform_kernel<<<dim3(F * 64), dim3(256), 0, stream>>>(x, Mc, out);
}